// Round 4
// baseline (95.466 us; speedup 1.0000x reference)
//
#include <hip/hip_runtime.h>

#define EMBED 256
#define NPOS  2304   // 48*48
#define BATCH 4
#define NH    8
#define DH    32

typedef float f32x4  __attribute__((ext_vector_type(4)));
typedef short bf16x8 __attribute__((ext_vector_type(8)));
typedef short s16x4  __attribute__((ext_vector_type(4)));
typedef unsigned u32x4 __attribute__((ext_vector_type(4)));

static __device__ __forceinline__ short f2b(float f) {
    union { float f; unsigned u; } c; c.f = f;
    unsigned r = (c.u + 0x7FFFu + ((c.u >> 16) & 1u)) >> 16;
    return (short)r;
}

static __device__ __forceinline__ unsigned cvtpk(float lo, float hi) {
    unsigned r;
    asm("v_cvt_pk_bf16_f32 %0, %1, %2" : "=v"(r) : "v"(lo), "v"(hi));
    return r;
}

static __device__ __forceinline__ float fexp2(float x) {
    float r;
    asm("v_exp_f32 %0, %1" : "=v"(r) : "v"(x));
    return r;
}

static __device__ __forceinline__ void plswap32(unsigned& a, unsigned& b) {
    asm("v_permlane32_swap_b32 %0, %1" : "+v"(a), "+v"(b));
}
static __device__ __forceinline__ void plswap16(unsigned& a, unsigned& b) {
    asm("v_permlane16_swap_b32 %0, %1" : "+v"(a), "+v"(b));
}

// ---------------- kernel 1: weights->bf16 AND xs = transpose(x)+PE ----------------
__global__ __launch_bounds__(256) void prep_all(
        const float* __restrict__ x,
        const float* __restrict__ wq, const float* __restrict__ wk,
        const float* __restrict__ wv, const float* __restrict__ wo,
        short* __restrict__ wqkv, short* __restrict__ wob,
        short* __restrict__ xs) {
    __shared__ float xt[32][65];
    int blk = blockIdx.x;
    int t = threadIdx.x;
    if (blk < 1024) {
        int g = blk * 256 + t;
        if (g < 196608) {
            int j = g >> 8, kk = g & 255;
            int proj = j >> 8, jj = j & 255;
            const float* s = (proj == 0) ? wq : (proj == 1) ? wk : wv;
            wqkv[g] = f2b(s[jj * 256 + kk]);
        } else if (g < 262144) {
            int h2 = g - 196608;
            wob[h2] = f2b(wo[h2]);
        }
        return;
    }
    int bx = blk - 1024;
    int b = bx / 288, rem = bx % 288;
    int c0 = (rem / 36) * 32, pos0 = (rem % 36) * 64;
    int j = t & 63, i0 = t >> 6;
    const float* xp = x + (size_t)(b * EMBED + c0) * NPOS + pos0;
#pragma unroll
    for (int rr = 0; rr < 8; ++rr) {
        int i = rr * 4 + i0;
        xt[i][j] = xp[(size_t)i * NPOS + j];
    }
    __syncthreads();
    int ii = (t & 15) * 2, jj0 = t >> 4;
    const float kln = -0.07195578415606394f;  // -ln(10000)/128
#pragma unroll
    for (int pp = 0; pp < 4; ++pp) {
        int jj = pp * 16 + jj0;
        int pos = pos0 + jj;
        float v0 = xt[ii][jj], v1 = xt[ii + 1][jj];
        float pe0 = 0.f, pe1 = 0.f;
        if (pos > 0) {
            int c = c0 + ii;
            float a0 = (float)pos * __expf((float)c * kln);
            float a1 = (float)pos * __expf((float)(c + 1) * kln);
            pe0 = __sinf(a0);   // even col -> sin
            pe1 = __cosf(a1);   // odd col -> cos
        }
        unsigned lo = (unsigned short)f2b(v0 + pe0);
        unsigned hi = (unsigned short)f2b(v1 + pe1);
        *reinterpret_cast<unsigned*>(xs + (size_t)(b * NPOS + pos) * EMBED + c0 + ii) =
            lo | (hi << 16);
    }
}

// ---------------- kernel 2: QKV GEMM (64x64 tiles, bias in C-init) ----------------
__global__ __launch_bounds__(256) void gemm_qkv(
        const short* __restrict__ A, const short* __restrict__ Bw,
        const float* __restrict__ bq, const float* __restrict__ bk,
        const float* __restrict__ bv,
        short* __restrict__ qd, short* __restrict__ kd, short* __restrict__ vtd) {
    __shared__ short a_sm[64 * 32];
    __shared__ short b_sm[64 * 32];
    int bx = blockIdx.x;            // 144 x 12
    int bm = bx / 12, bn = bx % 12;
    int m0 = bm * 64, n0 = bn * 64;
    int t = threadIdx.x;
    int lane = t & 63, wid = t >> 6;
    int wm = wid >> 1, wn = wid & 1;
    int l15 = lane & 15, l4 = lane >> 4;

    f32x4 acc[2][2];
#pragma unroll
    for (int ni = 0; ni < 2; ++ni) {
        int jcol = n0 + wn * 32 + ni * 16 + l15;
        int proj = jcol >> 8, jj = jcol & 255;
        float bias = ((proj == 0) ? bq : (proj == 1) ? bk : bv)[jj];
        f32x4 bi = {bias, bias, bias, bias};
        acc[0][ni] = bi;
        acc[1][ni] = bi;
    }

    int srow = t >> 2, sblk = t & 3;
    int ssw = (sblk ^ ((srow >> 1) & 3)) * 8;
    const short* ag = &A[(size_t)(m0 + srow) * 256 + sblk * 8];
    const short* bg = &Bw[(size_t)(n0 + srow) * 256 + sblk * 8];
    short* al = &a_sm[srow * 32 + ssw];
    short* bl = &b_sm[srow * 32 + ssw];

    for (int ks = 0; ks < 8; ++ks) {
        __syncthreads();
        *(bf16x8*)al = *(const bf16x8*)(ag + ks * 32);
        *(bf16x8*)bl = *(const bf16x8*)(bg + ks * 32);
        __syncthreads();
        bf16x8 af[2], bf[2];
#pragma unroll
        for (int mi = 0; mi < 2; ++mi) {
            int ar = wm * 32 + mi * 16 + l15;
            af[mi] = *(const bf16x8*)&a_sm[ar * 32 + ((l4 ^ ((ar >> 1) & 3)) * 8)];
        }
#pragma unroll
        for (int ni = 0; ni < 2; ++ni) {
            int br = wn * 32 + ni * 16 + l15;
            bf[ni] = *(const bf16x8*)&b_sm[br * 32 + ((l4 ^ ((br >> 1) & 3)) * 8)];
        }
#pragma unroll
        for (int mi = 0; mi < 2; ++mi)
#pragma unroll
            for (int ni = 0; ni < 2; ++ni)
                acc[mi][ni] = __builtin_amdgcn_mfma_f32_16x16x32_bf16(
                    af[mi], bf[ni], acc[mi][ni], 0, 0, 0);
    }

    const float qs = 0.2550348623f;  // log2(e)/sqrt(32)
#pragma unroll
    for (int mi = 0; mi < 2; ++mi) {
        int rowb = m0 + wm * 32 + mi * 16 + l4 * 4;
        int b = rowb / NPOS;
        int pos = rowb - b * NPOS;
#pragma unroll
        for (int ni = 0; ni < 2; ++ni) {
            int jcol = n0 + wn * 32 + ni * 16 + l15;
            int proj = jcol >> 8, jj = jcol & 255;
            int h = jj >> 5, d = jj & 31;
            if (proj == 2) {
                s16x4 pk;
#pragma unroll
                for (int r = 0; r < 4; ++r) pk[r] = f2b(acc[mi][ni][r]);
                *(s16x4*)&vtd[((size_t)(b * NH + h) * DH + d) * NPOS + pos] = pk;
            } else {
                short* dst = (proj == 0) ? qd : kd;
                float sc = (proj == 0) ? qs : 1.0f;
#pragma unroll
                for (int r = 0; r < 4; ++r)
                    dst[((size_t)(b * NH + h) * NPOS + pos + r) * DH + d] =
                        f2b(acc[mi][ni][r] * sc);
            }
        }
    }
}

// ---------------- kernel 3: flash attention (split-KV, all-register, no barriers) ----------------
// Q,K [bh][n][dh] bf16 (Q pre-scaled by log2e/sqrt(dh)), VT [bh][dh][n] bf16 -> AO [b][n][c] bf16
// Block = 128 thr (2 waves) = 32 q-rows; wave w handles KV tiles [w*18, w*18+18).
// K/V fragments load straight from global (L2-resident) into MFMA operand registers.

static __device__ __forceinline__ void attn_tile(
        const bf16x8 kf[4], const bf16x8 vf[4], const bf16x8 qf[2],
        f32x4 o[2][2], float ls[2], const f32x4& mb) {
#pragma unroll
    for (int qt = 0; qt < 2; ++qt) {
        f32x4 s0 = __builtin_amdgcn_mfma_f32_16x16x32_bf16(kf[0], qf[qt], mb, 0, 0, 0);
        f32x4 s1 = __builtin_amdgcn_mfma_f32_16x16x32_bf16(kf[1], qf[qt], mb, 0, 0, 0);
        f32x4 s2 = __builtin_amdgcn_mfma_f32_16x16x32_bf16(kf[2], qf[qt], mb, 0, 0, 0);
        f32x4 s3 = __builtin_amdgcn_mfma_f32_16x16x32_bf16(kf[3], qf[qt], mb, 0, 0, 0);

        float e00 = fexp2(s0[0]), e01 = fexp2(s0[1]), e02 = fexp2(s0[2]), e03 = fexp2(s0[3]);
        float e10 = fexp2(s1[0]), e11 = fexp2(s1[1]), e12 = fexp2(s1[2]), e13 = fexp2(s1[3]);
        float e20 = fexp2(s2[0]), e21 = fexp2(s2[1]), e22 = fexp2(s2[2]), e23 = fexp2(s2[3]);
        float e30 = fexp2(s3[0]), e31 = fexp2(s3[1]), e32 = fexp2(s3[2]), e33 = fexp2(s3[3]);
        ls[qt] += (((e00 + e01) + (e02 + e03)) + ((e10 + e11) + (e12 + e13)))
                + (((e20 + e21) + (e22 + e23)) + ((e30 + e31) + (e32 + e33)));

        unsigned p00 = cvtpk(e00, e01), p01 = cvtpk(e02, e03);
        unsigned p10 = cvtpk(e10, e11), p11 = cvtpk(e12, e13);
        unsigned p20 = cvtpk(e20, e21), p21 = cvtpk(e22, e23);
        unsigned p30 = cvtpk(e30, e31), p31 = cvtpk(e32, e33);

        // kh=0 B-frag from (p0x, p1x); kh=1 from (p2x, p3x)
        unsigned a0 = p00, b0 = p10;
        plswap32(a0, b0); plswap16(a0, b0);
        unsigned a1 = p01, b1 = p11;
        plswap32(a1, b1); plswap16(a1, b1);
        u32x4 fr0 = {a0, a1, b0, b1};
        bf16x8 pf0 = __builtin_bit_cast(bf16x8, fr0);
        unsigned c0 = p20, d0 = p30;
        plswap32(c0, d0); plswap16(c0, d0);
        unsigned c1 = p21, d1 = p31;
        plswap32(c1, d1); plswap16(c1, d1);
        u32x4 fr1 = {c0, c1, d0, d1};
        bf16x8 pf1 = __builtin_bit_cast(bf16x8, fr1);

        o[0][qt] = __builtin_amdgcn_mfma_f32_16x16x32_bf16(vf[0], pf0, o[0][qt], 0, 0, 0);
        o[1][qt] = __builtin_amdgcn_mfma_f32_16x16x32_bf16(vf[1], pf0, o[1][qt], 0, 0, 0);
        o[0][qt] = __builtin_amdgcn_mfma_f32_16x16x32_bf16(vf[2], pf1, o[0][qt], 0, 0, 0);
        o[1][qt] = __builtin_amdgcn_mfma_f32_16x16x32_bf16(vf[3], pf1, o[1][qt], 0, 0, 0);
    }
}

static __device__ __forceinline__ void load_tile(
        const short* kgl, const short* vgl, int kv, bf16x8 kf[4], bf16x8 vf[4]) {
#pragma unroll
    for (int sub = 0; sub < 4; ++sub)
        kf[sub] = *(const bf16x8*)(kgl + (size_t)(kv + sub * 16) * DH);
#pragma unroll
    for (int kh = 0; kh < 2; ++kh)
#pragma unroll
        for (int dt2 = 0; dt2 < 2; ++dt2)
            vf[kh * 2 + dt2] = *(const bf16x8*)(vgl + (size_t)dt2 * 16 * NPOS + kv + kh * 32);
}

__global__ __launch_bounds__(128) void attn_fwd(
        const short* __restrict__ Q, const short* __restrict__ K,
        const short* __restrict__ VT, short* __restrict__ AO) {
    __shared__ f32x4 o_sm[4][64];
    __shared__ float l_sm[2][64];

    int bx0 = blockIdx.x;
    int bx = (bx0 & 7) * 288 + (bx0 >> 3);   // 2304 = 8*288: bijective, same-bh -> same XCD
    int bh = bx / 72, qt0 = bx % 72;
    int q0 = qt0 * 32;
    int t = threadIdx.x, lane = t & 63, wid = t >> 6;
    int l15 = lane & 15, l4 = lane >> 4;

    // Q B-frags for this block's 32 q-rows (both waves identical)
    const short* Qb = Q + ((size_t)bh * NPOS + q0) * DH;
    bf16x8 qf[2];
    qf[0] = *(const bf16x8*)&Qb[l15 * DH + l4 * 8];
    qf[1] = *(const bf16x8*)&Qb[(16 + l15) * DH + l4 * 8];

    // per-lane fragment base addresses
    const short* kgl = K + ((size_t)bh * NPOS + l15) * DH + l4 * 8;
    const short* vgl = VT + ((size_t)bh * DH + l15) * NPOS + l4 * 8;

    f32x4 zero = {0.f, 0.f, 0.f, 0.f};
    f32x4 o[2][2];
    o[0][0] = zero; o[0][1] = zero; o[1][0] = zero; o[1][1] = zero;
    float ls[2] = {0.f, 0.f};
    const float MB = -17.312340490667561f;  // -12*log2(e)
    const f32x4 mb = {MB, MB, MB, MB};

    int kvbase = wid * 1152;                 // 18 tiles of 64 keys per wave

    bf16x8 kA[4], vA[4], kB[4], vB[4];
    load_tile(kgl, vgl, kvbase, kA, vA);
#pragma unroll 1
    for (int tt = 0; tt < 18; tt += 2) {
        load_tile(kgl, vgl, kvbase + (tt + 1) * 64, kB, vB);
        attn_tile(kA, vA, qf, o, ls, mb);
        if (tt + 2 < 18)
            load_tile(kgl, vgl, kvbase + (tt + 2) * 64, kA, vA);
        attn_tile(kB, vB, qf, o, ls, mb);
    }

    // intra-wave l reduction (sum over l4 groups)
#pragma unroll
    for (int qt = 0; qt < 2; ++qt) {
        ls[qt] += __shfl_xor(ls[qt], 16);
        ls[qt] += __shfl_xor(ls[qt], 32);
    }

    // cross-wave combine via LDS
    if (wid == 1) {
#pragma unroll
        for (int qt = 0; qt < 2; ++qt) {
            l_sm[qt][lane] = ls[qt];
#pragma unroll
            for (int dt2 = 0; dt2 < 2; ++dt2)
                o_sm[qt * 2 + dt2][lane] = o[dt2][qt];
        }
    }
    __syncthreads();
    if (wid == 0) {
        int b = bh >> 3, h = bh & 7;
#pragma unroll
        for (int qt = 0; qt < 2; ++qt) {
            float lt = ls[qt] + l_sm[qt][lane];
            float inv = __builtin_amdgcn_rcpf(lt);
            int qrow = q0 + qt * 16 + l15;
            size_t obase = ((size_t)b * NPOS + qrow) * EMBED + h * DH;
#pragma unroll
            for (int dt2 = 0; dt2 < 2; ++dt2) {
                f32x4 ot = o[dt2][qt] + o_sm[qt * 2 + dt2][lane];
                unsigned x0 = cvtpk(ot[0] * inv, ot[1] * inv);
                unsigned x1 = cvtpk(ot[2] * inv, ot[3] * inv);
                *(unsigned long long*)&AO[obase + dt2 * 16 + l4 * 4] =
                    (unsigned long long)x0 | ((unsigned long long)x1 << 32);
            }
        }
    }
}

// ---------------- kernel 4: out projection + transpose (32x64 tiles) ----------------
__global__ __launch_bounds__(256) void gemm_out(
        const short* __restrict__ A, const short* __restrict__ Bw,
        const float* __restrict__ bo, float* __restrict__ out) {
    __shared__ short a_sm[32 * 32];
    __shared__ short b_sm[64 * 32];
    int bx = blockIdx.x;             // 288 x 4
    int bm = bx >> 2, bn = bx & 3;
    int m0 = bm * 32, n0 = bn * 64;
    int t = threadIdx.x;
    int lane = t & 63, wid = t >> 6;
    int wm = wid >> 1, wn = wid & 1;
    int l15 = lane & 15, l4 = lane >> 4;

    f32x4 acc[2];
#pragma unroll
    for (int ni = 0; ni < 2; ++ni) {
        float bias = bo[n0 + wn * 32 + ni * 16 + l15];
        f32x4 bi = {bias, bias, bias, bias};
        acc[ni] = bi;
    }

    int srow = t >> 2, sblk = t & 3;
    int ssw = (sblk ^ ((srow >> 1) & 3)) * 8;
    const short* ag = &A[(size_t)(m0 + srow) * 256 + sblk * 8];
    const short* bg = &Bw[(size_t)(n0 + srow) * 256 + sblk * 8];
    short* al = &a_sm[srow * 32 + ssw];
    short* bl = &b_sm[srow * 32 + ssw];

    for (int ks = 0; ks < 8; ++ks) {
        __syncthreads();
        if (t < 128) *(bf16x8*)al = *(const bf16x8*)(ag + ks * 32);
        *(bf16x8*)bl = *(const bf16x8*)(bg + ks * 32);
        __syncthreads();
        int ar = wm * 16 + l15;
        bf16x8 af = *(const bf16x8*)&a_sm[ar * 32 + ((l4 ^ ((ar >> 1) & 3)) * 8)];
        bf16x8 bf[2];
#pragma unroll
        for (int ni = 0; ni < 2; ++ni) {
            int br = wn * 32 + ni * 16 + l15;
            bf[ni] = *(const bf16x8*)&b_sm[br * 32 + ((l4 ^ ((br >> 1) & 3)) * 8)];
        }
#pragma unroll
        for (int ni = 0; ni < 2; ++ni)
            acc[ni] = __builtin_amdgcn_mfma_f32_16x16x32_bf16(af, bf[ni], acc[ni], 0, 0, 0);
    }

    int rowb = m0 + wm * 16 + l4 * 4;
    int b = rowb / NPOS;
    int pos = rowb - b * NPOS;
#pragma unroll
    for (int ni = 0; ni < 2; ++ni) {
        int jcol = n0 + wn * 32 + ni * 16 + l15;
        *(f32x4*)&out[((size_t)(b * EMBED) + jcol) * NPOS + pos] = acc[ni];
    }
}

extern "C" void kernel_launch(void* const* d_in, const int* in_sizes, int n_in,
                              void* d_out, int out_size, void* d_ws, size_t ws_size,
                              hipStream_t stream) {
    const float* x  = (const float*)d_in[0];
    const float* wq = (const float*)d_in[1];
    const float* bq = (const float*)d_in[2];
    const float* wk = (const float*)d_in[3];
    const float* bk = (const float*)d_in[4];
    const float* wv = (const float*)d_in[5];
    const float* bv = (const float*)d_in[6];
    const float* wo = (const float*)d_in[7];
    const float* bo = (const float*)d_in[8];

    char* ws = (char*)d_ws;
    short* wqkv = (short*)(ws);               // 768*256*2   = 393216
    short* wob  = (short*)(ws + 393216);      // 256*256*2   = 131072
    short* xs   = (short*)(ws + 524288);      // 9216*256*2  = 4718592
    short* qb   = (short*)(ws + 5242880);     // 4718592
    short* kb   = (short*)(ws + 9961472);     // 4718592
    short* vtb  = (short*)(ws + 14680064);    // 4718592
    short* ao   = (short*)(ws + 19398656);    // 4718592 -> total 24117248
    float* out  = (float*)d_out;

    hipLaunchKernelGGL(prep_all, dim3(2176), dim3(256), 0, stream,
                       x, wq, wk, wv, wo, wqkv, wob, xs);
    hipLaunchKernelGGL(gemm_qkv, dim3(1728), dim3(256), 0, stream,
                       xs, wqkv, bq, bk, bv, qb, kb, vtb);
    hipLaunchKernelGGL(attn_fwd, dim3(2304), dim3(128), 0, stream, qb, kb, vtb, ao);
    hipLaunchKernelGGL(gemm_out, dim3(1152), dim3(256), 0, stream, ao, wob, bo, out);
}

// Round 6
// 85.828 us; speedup vs baseline: 1.1123x; 1.1123x over previous
//
#include <hip/hip_runtime.h>

#define EMBED 256
#define NPOS  2304   // 48*48
#define BATCH 4
#define NH    8
#define DH    32

typedef float f32x4  __attribute__((ext_vector_type(4)));
typedef short bf16x8 __attribute__((ext_vector_type(8)));
typedef short s16x4  __attribute__((ext_vector_type(4)));
typedef unsigned u32x4 __attribute__((ext_vector_type(4)));

static __device__ __forceinline__ short f2b(float f) {
    union { float f; unsigned u; } c; c.f = f;
    unsigned r = (c.u + 0x7FFFu + ((c.u >> 16) & 1u)) >> 16;
    return (short)r;
}

static __device__ __forceinline__ unsigned cvtpk(float lo, float hi) {
    unsigned r;
    asm("v_cvt_pk_bf16_f32 %0, %1, %2" : "=v"(r) : "v"(lo), "v"(hi));
    return r;
}

static __device__ __forceinline__ float fexp2(float x) {
    float r;
    asm("v_exp_f32 %0, %1" : "=v"(r) : "v"(x));
    return r;
}

static __device__ __forceinline__ void plswap32(unsigned& a, unsigned& b) {
    asm("v_permlane32_swap_b32 %0, %1" : "+v"(a), "+v"(b));
}
static __device__ __forceinline__ void plswap16(unsigned& a, unsigned& b) {
    asm("v_permlane16_swap_b32 %0, %1" : "+v"(a), "+v"(b));
}

static __device__ __forceinline__ void gl_lds16(const short* g, short* l) {
    __builtin_amdgcn_global_load_lds(
        (const __attribute__((address_space(1))) unsigned int*)(g),
        (__attribute__((address_space(3))) unsigned int*)(l),
        16, 0, 0);
}

// ---------------- kernel 1: weights->bf16 AND xs = transpose(x)+PE ----------------
__global__ __launch_bounds__(256) void prep_all(
        const float* __restrict__ x,
        const float* __restrict__ wq, const float* __restrict__ wk,
        const float* __restrict__ wv, const float* __restrict__ wo,
        short* __restrict__ wqkv, short* __restrict__ wob,
        short* __restrict__ xs) {
    __shared__ float xt[32][65];
    int blk = blockIdx.x;
    int t = threadIdx.x;
    if (blk < 1024) {
        int g = blk * 256 + t;
        if (g < 196608) {
            int j = g >> 8, kk = g & 255;
            int proj = j >> 8, jj = j & 255;
            const float* s = (proj == 0) ? wq : (proj == 1) ? wk : wv;
            wqkv[g] = f2b(s[jj * 256 + kk]);
        } else if (g < 262144) {
            int h2 = g - 196608;
            wob[h2] = f2b(wo[h2]);
        }
        return;
    }
    int bx = blk - 1024;
    int b = bx / 288, rem = bx % 288;
    int c0 = (rem / 36) * 32, pos0 = (rem % 36) * 64;
    int j = t & 63, i0 = t >> 6;
    const float* xp = x + (size_t)(b * EMBED + c0) * NPOS + pos0;
#pragma unroll
    for (int rr = 0; rr < 8; ++rr) {
        int i = rr * 4 + i0;
        xt[i][j] = xp[(size_t)i * NPOS + j];
    }
    __syncthreads();
    int ii = (t & 15) * 2, jj0 = t >> 4;
    const float kln = -0.07195578415606394f;  // -ln(10000)/128
#pragma unroll
    for (int pp = 0; pp < 4; ++pp) {
        int jj = pp * 16 + jj0;
        int pos = pos0 + jj;
        float v0 = xt[ii][jj], v1 = xt[ii + 1][jj];
        float pe0 = 0.f, pe1 = 0.f;
        if (pos > 0) {
            int c = c0 + ii;
            float a0 = (float)pos * __expf((float)c * kln);
            float a1 = (float)pos * __expf((float)(c + 1) * kln);
            pe0 = __sinf(a0);   // even col -> sin
            pe1 = __cosf(a1);   // odd col -> cos
        }
        unsigned lo = (unsigned short)f2b(v0 + pe0);
        unsigned hi = (unsigned short)f2b(v1 + pe1);
        *reinterpret_cast<unsigned*>(xs + (size_t)(b * NPOS + pos) * EMBED + c0 + ii) =
            lo | (hi << 16);
    }
}

// ---------------- kernel 2: QKV GEMM (64x64 tiles, bias in C-init) ----------------
__global__ __launch_bounds__(256) void gemm_qkv(
        const short* __restrict__ A, const short* __restrict__ Bw,
        const float* __restrict__ bq, const float* __restrict__ bk,
        const float* __restrict__ bv,
        short* __restrict__ qd, short* __restrict__ kd, short* __restrict__ vtd) {
    __shared__ short a_sm[64 * 32];
    __shared__ short b_sm[64 * 32];
    int bx = blockIdx.x;            // 144 x 12
    int bm = bx / 12, bn = bx % 12;
    int m0 = bm * 64, n0 = bn * 64;
    int t = threadIdx.x;
    int lane = t & 63, wid = t >> 6;
    int wm = wid >> 1, wn = wid & 1;
    int l15 = lane & 15, l4 = lane >> 4;

    f32x4 acc[2][2];
#pragma unroll
    for (int ni = 0; ni < 2; ++ni) {
        int jcol = n0 + wn * 32 + ni * 16 + l15;
        int proj = jcol >> 8, jj = jcol & 255;
        float bias = ((proj == 0) ? bq : (proj == 1) ? bk : bv)[jj];
        f32x4 bi = {bias, bias, bias, bias};
        acc[0][ni] = bi;
        acc[1][ni] = bi;
    }

    int srow = t >> 2, sblk = t & 3;
    int ssw = (sblk ^ ((srow >> 1) & 3)) * 8;
    const short* ag = &A[(size_t)(m0 + srow) * 256 + sblk * 8];
    const short* bg = &Bw[(size_t)(n0 + srow) * 256 + sblk * 8];
    short* al = &a_sm[srow * 32 + ssw];
    short* bl = &b_sm[srow * 32 + ssw];

    for (int ks = 0; ks < 8; ++ks) {
        __syncthreads();
        *(bf16x8*)al = *(const bf16x8*)(ag + ks * 32);
        *(bf16x8*)bl = *(const bf16x8*)(bg + ks * 32);
        __syncthreads();
        bf16x8 af[2], bf[2];
#pragma unroll
        for (int mi = 0; mi < 2; ++mi) {
            int ar = wm * 32 + mi * 16 + l15;
            af[mi] = *(const bf16x8*)&a_sm[ar * 32 + ((l4 ^ ((ar >> 1) & 3)) * 8)];
        }
#pragma unroll
        for (int ni = 0; ni < 2; ++ni) {
            int br = wn * 32 + ni * 16 + l15;
            bf[ni] = *(const bf16x8*)&b_sm[br * 32 + ((l4 ^ ((br >> 1) & 3)) * 8)];
        }
#pragma unroll
        for (int mi = 0; mi < 2; ++mi)
#pragma unroll
            for (int ni = 0; ni < 2; ++ni)
                acc[mi][ni] = __builtin_amdgcn_mfma_f32_16x16x32_bf16(
                    af[mi], bf[ni], acc[mi][ni], 0, 0, 0);
    }

    const float qs = 0.2550348623f;  // log2(e)/sqrt(32)
#pragma unroll
    for (int mi = 0; mi < 2; ++mi) {
        int rowb = m0 + wm * 32 + mi * 16 + l4 * 4;
        int b = rowb / NPOS;
        int pos = rowb - b * NPOS;
#pragma unroll
        for (int ni = 0; ni < 2; ++ni) {
            int jcol = n0 + wn * 32 + ni * 16 + l15;
            int proj = jcol >> 8, jj = jcol & 255;
            int h = jj >> 5, d = jj & 31;
            if (proj == 2) {
                s16x4 pk;
#pragma unroll
                for (int r = 0; r < 4; ++r) pk[r] = f2b(acc[mi][ni][r]);
                *(s16x4*)&vtd[((size_t)(b * NH + h) * DH + d) * NPOS + pos] = pk;
            } else {
                short* dst = (proj == 0) ? qd : kd;
                float sc = (proj == 0) ? qs : 1.0f;
#pragma unroll
                for (int r = 0; r < 4; ++r)
                    dst[((size_t)(b * NH + h) * NPOS + pos + r) * DH + d] =
                        f2b(acc[mi][ni][r] * sc);
            }
        }
    }
}

// ---------------- kernel 3: flash attention ----------------
// 2 waves/block; wave owns 32 q-rows (qf[2]); K/V staged via global_load_lds,
// 3-deep double buffer, counted vmcnt (DMA-queue MLP, no VGPR cost).
// Q,K [bh][n][dh] bf16 (Q pre-scaled by log2e/sqrt(dh)), VT [bh][dh][n] -> AO bf16

static __device__ __forceinline__ void issue_tile(
        const short* kg, const short* vg, int kv0, short* kdst, short* vdst) {
    gl_lds16(kg + (size_t)kv0 * DH,        kdst);
    gl_lds16(kg + (size_t)(kv0 + 32) * DH, kdst + 1024);
    gl_lds16(vg + kv0,                     vdst);
    gl_lds16(vg + kv0 + 16 * NPOS,         vdst + 1024);
}

__global__ __launch_bounds__(128) void attn_fwd(
        const short* __restrict__ Q, const short* __restrict__ K,
        const short* __restrict__ VT, short* __restrict__ AO) {
    __shared__ short k_sm[3][2048];    // [buf][key 64][dh 32], 16B blk swizzle blk^((key>>1)&3)
    __shared__ short vt_sm[3][2048];   // [buf][d 32][key 64],  16B blk swizzle blk^(d&7)

    int bx0 = blockIdx.x;
    int bx = (bx0 & 7) * 144 + (bx0 >> 3);   // 1152 = 8*144: bijective, same-bh -> same XCD
    int bh = bx / 36, qt0 = bx % 36;
    int q0 = qt0 * 64;
    int t = threadIdx.x, lane = t & 63, wid = t >> 6;
    int l15 = lane & 15, l4 = lane >> 4;

    // Q B-frags: wave wid owns qrows q0 + wid*32 + [0,32)
    const short* Qb = Q + ((size_t)bh * NPOS + q0 + wid * 32) * DH;
    bf16x8 qf[2];
    qf[0] = *(const bf16x8*)&Qb[l15 * DH + l4 * 8];
    qf[1] = *(const bf16x8*)&Qb[(16 + l15) * DH + l4 * 8];

    // staging sources (pre-swizzled global addr; LDS dest linear)
    int krow = t >> 2, kblk = t & 3;   // rows 0..31 (+32 in 2nd DMA)
    const short* kg = K + ((size_t)bh * NPOS + krow) * DH + ((kblk ^ ((krow >> 1) & 3)) * 8);
    int vrow = t >> 3, vblk = t & 7;   // d 0..15 (+16)
    const short* vg = VT + ((size_t)bh * DH + vrow) * NPOS + ((vblk ^ (vrow & 7)) * 8);
    int dbase = wid * 512;             // per-wave LDS dest base (shorts)

    f32x4 zero = {0.f, 0.f, 0.f, 0.f};
    f32x4 o[2][2];
    o[0][0] = zero; o[0][1] = zero; o[1][0] = zero; o[1][1] = zero;
    float ls[2] = {0.f, 0.f};
    const float MB = -17.312340490667561f;  // -12*log2(e)
    const f32x4 mb = {MB, MB, MB, MB};

    // read-side swizzles (independent of tile)
    int ksw = (l4 ^ ((l15 >> 1) & 3)) * 8;
    int vsw0 = (l4 ^ (l15 & 7)) * 8;
    int vsw1 = ((4 + l4) ^ (l15 & 7)) * 8;

    issue_tile(kg, vg, 0,  &k_sm[0][dbase], &vt_sm[0][dbase]);
    issue_tile(kg, vg, 64, &k_sm[1][dbase], &vt_sm[1][dbase]);

    int cur = 0;
#pragma unroll 1
    for (int tt = 0; tt < 36; ++tt) {
        if (tt + 2 < 36) {
            int nb = cur + 2; if (nb >= 3) nb -= 3;
            issue_tile(kg, vg, (tt + 2) * 64, &k_sm[nb][dbase], &vt_sm[nb][dbase]);
            asm volatile("s_waitcnt vmcnt(8)" ::: "memory");
        } else if (tt + 1 < 36) {
            asm volatile("s_waitcnt vmcnt(4)" ::: "memory");
        } else {
            asm volatile("s_waitcnt vmcnt(0)" ::: "memory");
        }
        __builtin_amdgcn_s_barrier();
        asm volatile("" ::: "memory");

        const short* kb = k_sm[cur];
        const short* vb = vt_sm[cur];

        bf16x8 kf[4], vf[4];
        kf[0] = *(const bf16x8*)&kb[(l15)      * 32 + ksw];
        kf[1] = *(const bf16x8*)&kb[(16 + l15) * 32 + ksw];
        kf[2] = *(const bf16x8*)&kb[(32 + l15) * 32 + ksw];
        kf[3] = *(const bf16x8*)&kb[(48 + l15) * 32 + ksw];
        vf[0] = *(const bf16x8*)&vb[(l15)      * 64 + vsw0];
        vf[1] = *(const bf16x8*)&vb[(16 + l15) * 64 + vsw0];
        vf[2] = *(const bf16x8*)&vb[(l15)      * 64 + vsw1];
        vf[3] = *(const bf16x8*)&vb[(16 + l15) * 64 + vsw1];

#pragma unroll
        for (int qt = 0; qt < 2; ++qt) {
            f32x4 s0 = __builtin_amdgcn_mfma_f32_16x16x32_bf16(kf[0], qf[qt], mb, 0, 0, 0);
            f32x4 s1 = __builtin_amdgcn_mfma_f32_16x16x32_bf16(kf[1], qf[qt], mb, 0, 0, 0);
            f32x4 s2 = __builtin_amdgcn_mfma_f32_16x16x32_bf16(kf[2], qf[qt], mb, 0, 0, 0);
            f32x4 s3 = __builtin_amdgcn_mfma_f32_16x16x32_bf16(kf[3], qf[qt], mb, 0, 0, 0);

            float e00 = fexp2(s0[0]), e01 = fexp2(s0[1]), e02 = fexp2(s0[2]), e03 = fexp2(s0[3]);
            float e10 = fexp2(s1[0]), e11 = fexp2(s1[1]), e12 = fexp2(s1[2]), e13 = fexp2(s1[3]);
            float e20 = fexp2(s2[0]), e21 = fexp2(s2[1]), e22 = fexp2(s2[2]), e23 = fexp2(s2[3]);
            float e30 = fexp2(s3[0]), e31 = fexp2(s3[1]), e32 = fexp2(s3[2]), e33 = fexp2(s3[3]);
            ls[qt] += (((e00 + e01) + (e02 + e03)) + ((e10 + e11) + (e12 + e13)))
                    + (((e20 + e21) + (e22 + e23)) + ((e30 + e31) + (e32 + e33)));

            unsigned p00 = cvtpk(e00, e01), p01 = cvtpk(e02, e03);
            unsigned p10 = cvtpk(e10, e11), p11 = cvtpk(e12, e13);
            unsigned p20 = cvtpk(e20, e21), p21 = cvtpk(e22, e23);
            unsigned p30 = cvtpk(e30, e31), p31 = cvtpk(e32, e33);

            unsigned a0 = p00, b0 = p10;
            plswap32(a0, b0); plswap16(a0, b0);
            unsigned a1 = p01, b1 = p11;
            plswap32(a1, b1); plswap16(a1, b1);
            u32x4 fr0 = {a0, a1, b0, b1};
            bf16x8 pf0 = __builtin_bit_cast(bf16x8, fr0);
            unsigned c0 = p20, d0 = p30;
            plswap32(c0, d0); plswap16(c0, d0);
            unsigned c1 = p21, d1 = p31;
            plswap32(c1, d1); plswap16(c1, d1);
            u32x4 fr1 = {c0, c1, d0, d1};
            bf16x8 pf1 = __builtin_bit_cast(bf16x8, fr1);

            o[0][qt] = __builtin_amdgcn_mfma_f32_16x16x32_bf16(vf[0], pf0, o[0][qt], 0, 0, 0);
            o[1][qt] = __builtin_amdgcn_mfma_f32_16x16x32_bf16(vf[1], pf0, o[1][qt], 0, 0, 0);
            o[0][qt] = __builtin_amdgcn_mfma_f32_16x16x32_bf16(vf[2], pf1, o[0][qt], 0, 0, 0);
            o[1][qt] = __builtin_amdgcn_mfma_f32_16x16x32_bf16(vf[3], pf1, o[1][qt], 0, 0, 0);
        }
        asm volatile("" ::: "memory");
        __builtin_amdgcn_s_barrier();
        asm volatile("" ::: "memory");
        cur = cur + 1; if (cur >= 3) cur = 0;
    }

    float l0 = ls[0];
    l0 += __shfl_xor(l0, 16);
    l0 += __shfl_xor(l0, 32);
    float l1 = ls[1];
    l1 += __shfl_xor(l1, 16);
    l1 += __shfl_xor(l1, 32);
    float inv0 = __builtin_amdgcn_rcpf(l0);
    float inv1 = __builtin_amdgcn_rcpf(l1);

    int b = bh >> 3, h = bh & 7;
#pragma unroll
    for (int qt = 0; qt < 2; ++qt) {
        int qrow = q0 + wid * 32 + qt * 16 + l15;
        float inv = (qt == 0) ? inv0 : inv1;
        size_t obase = ((size_t)b * NPOS + qrow) * EMBED + h * DH;
#pragma unroll
        for (int dt2 = 0; dt2 < 2; ++dt2) {
            unsigned x0 = cvtpk(o[dt2][qt][0] * inv, o[dt2][qt][1] * inv);
            unsigned x1 = cvtpk(o[dt2][qt][2] * inv, o[dt2][qt][3] * inv);
            *(unsigned long long*)&AO[obase + dt2 * 16 + l4 * 4] =
                (unsigned long long)x0 | ((unsigned long long)x1 << 32);
        }
    }
}

// ---------------- kernel 4: out projection + transpose (32x64 tiles) ----------------
__global__ __launch_bounds__(256) void gemm_out(
        const short* __restrict__ A, const short* __restrict__ Bw,
        const float* __restrict__ bo, float* __restrict__ out) {
    __shared__ short a_sm[32 * 32];
    __shared__ short b_sm[64 * 32];
    int bx = blockIdx.x;             // 288 x 4
    int bm = bx >> 2, bn = bx & 3;
    int m0 = bm * 32, n0 = bn * 64;
    int t = threadIdx.x;
    int lane = t & 63, wid = t >> 6;
    int wm = wid >> 1, wn = wid & 1;
    int l15 = lane & 15, l4 = lane >> 4;

    f32x4 acc[2];
#pragma unroll
    for (int ni = 0; ni < 2; ++ni) {
        float bias = bo[n0 + wn * 32 + ni * 16 + l15];
        f32x4 bi = {bias, bias, bias, bias};
        acc[ni] = bi;
    }

    int srow = t >> 2, sblk = t & 3;
    int ssw = (sblk ^ ((srow >> 1) & 3)) * 8;
    const short* ag = &A[(size_t)(m0 + srow) * 256 + sblk * 8];
    const short* bg = &Bw[(size_t)(n0 + srow) * 256 + sblk * 8];
    short* al = &a_sm[srow * 32 + ssw];
    short* bl = &b_sm[srow * 32 + ssw];

    for (int ks = 0; ks < 8; ++ks) {
        __syncthreads();
        if (t < 128) *(bf16x8*)al = *(const bf16x8*)(ag + ks * 32);
        *(bf16x8*)bl = *(const bf16x8*)(bg + ks * 32);
        __syncthreads();
        int ar = wm * 16 + l15;
        bf16x8 af = *(const bf16x8*)&a_sm[ar * 32 + ((l4 ^ ((ar >> 1) & 3)) * 8)];
        bf16x8 bf[2];
#pragma unroll
        for (int ni = 0; ni < 2; ++ni) {
            int br = wn * 32 + ni * 16 + l15;
            bf[ni] = *(const bf16x8*)&b_sm[br * 32 + ((l4 ^ ((br >> 1) & 3)) * 8)];
        }
#pragma unroll
        for (int ni = 0; ni < 2; ++ni)
            acc[ni] = __builtin_amdgcn_mfma_f32_16x16x32_bf16(af, bf[ni], acc[ni], 0, 0, 0);
    }

    int rowb = m0 + wm * 16 + l4 * 4;
    int b = rowb / NPOS;
    int pos = rowb - b * NPOS;
#pragma unroll
    for (int ni = 0; ni < 2; ++ni) {
        int jcol = n0 + wn * 32 + ni * 16 + l15;
        *(f32x4*)&out[((size_t)(b * EMBED) + jcol) * NPOS + pos] = acc[ni];
    }
}

extern "C" void kernel_launch(void* const* d_in, const int* in_sizes, int n_in,
                              void* d_out, int out_size, void* d_ws, size_t ws_size,
                              hipStream_t stream) {
    const float* x  = (const float*)d_in[0];
    const float* wq = (const float*)d_in[1];
    const float* bq = (const float*)d_in[2];
    const float* wk = (const float*)d_in[3];
    const float* bk = (const float*)d_in[4];
    const float* wv = (const float*)d_in[5];
    const float* bv = (const float*)d_in[6];
    const float* wo = (const float*)d_in[7];
    const float* bo = (const float*)d_in[8];

    char* ws = (char*)d_ws;
    short* wqkv = (short*)(ws);               // 768*256*2   = 393216
    short* wob  = (short*)(ws + 393216);      // 256*256*2   = 131072
    short* xs   = (short*)(ws + 524288);      // 9216*256*2  = 4718592
    short* qb   = (short*)(ws + 5242880);     // 4718592
    short* kb   = (short*)(ws + 9961472);     // 4718592
    short* vtb  = (short*)(ws + 14680064);    // 4718592
    short* ao   = (short*)(ws + 19398656);    // 4718592 -> total 24117248
    float* out  = (float*)d_out;

    hipLaunchKernelGGL(prep_all, dim3(2176), dim3(256), 0, stream,
                       x, wq, wk, wv, wo, wqkv, wob, xs);
    hipLaunchKernelGGL(gemm_qkv, dim3(1728), dim3(256), 0, stream,
                       xs, wqkv, bq, bk, bv, qb, kb, vtb);
    hipLaunchKernelGGL(attn_fwd, dim3(1152), dim3(128), 0, stream, qb, kb, vtb, ao);
    hipLaunchKernelGGL(gemm_out, dim3(1152), dim3(256), 0, stream, ao, wob, bo, out);
}

// Round 7
// 73.535 us; speedup vs baseline: 1.2982x; 1.1672x over previous
//
#include <hip/hip_runtime.h>

#define EMBED 256
#define NPOS  2304   // 48*48
#define BATCH 4
#define NH    8
#define DH    32

typedef float f32x4  __attribute__((ext_vector_type(4)));
typedef short bf16x8 __attribute__((ext_vector_type(8)));
typedef short s16x4  __attribute__((ext_vector_type(4)));
typedef unsigned u32x4 __attribute__((ext_vector_type(4)));

static __device__ __forceinline__ short f2b(float f) {
    union { float f; unsigned u; } c; c.f = f;
    unsigned r = (c.u + 0x7FFFu + ((c.u >> 16) & 1u)) >> 16;
    return (short)r;
}

static __device__ __forceinline__ unsigned cvtpk(float lo, float hi) {
    unsigned r;
    asm("v_cvt_pk_bf16_f32 %0, %1, %2" : "=v"(r) : "v"(lo), "v"(hi));
    return r;
}

static __device__ __forceinline__ float fexp2(float x) {
    float r;
    asm("v_exp_f32 %0, %1" : "=v"(r) : "v"(x));
    return r;
}

static __device__ __forceinline__ void plswap32(unsigned& a, unsigned& b) {
    asm("v_permlane32_swap_b32 %0, %1" : "+v"(a), "+v"(b));
}
static __device__ __forceinline__ void plswap16(unsigned& a, unsigned& b) {
    asm("v_permlane16_swap_b32 %0, %1" : "+v"(a), "+v"(b));
}

static __device__ __forceinline__ void gl_lds16(const short* g, short* l) {
    __builtin_amdgcn_global_load_lds(
        (const __attribute__((address_space(1))) unsigned int*)(g),
        (__attribute__((address_space(3))) unsigned int*)(l),
        16, 0, 0);
}

// ---------------- kernel 1: weights->bf16 AND xs = transpose(x)+PE ----------------
__global__ __launch_bounds__(256) void prep_all(
        const float* __restrict__ x,
        const float* __restrict__ wq, const float* __restrict__ wk,
        const float* __restrict__ wv, const float* __restrict__ wo,
        short* __restrict__ wqkv, short* __restrict__ wob,
        short* __restrict__ xs) {
    __shared__ float xt[32][65];
    int blk = blockIdx.x;
    int t = threadIdx.x;
    if (blk < 1024) {
        int g = blk * 256 + t;
        if (g < 196608) {
            int j = g >> 8, kk = g & 255;
            int proj = j >> 8, jj = j & 255;
            const float* s = (proj == 0) ? wq : (proj == 1) ? wk : wv;
            wqkv[g] = f2b(s[jj * 256 + kk]);
        } else if (g < 262144) {
            int h2 = g - 196608;
            wob[h2] = f2b(wo[h2]);
        }
        return;
    }
    int bx = blk - 1024;
    int b = bx / 288, rem = bx % 288;
    int c0 = (rem / 36) * 32, pos0 = (rem % 36) * 64;
    int j = t & 63, i0 = t >> 6;
    const float* xp = x + (size_t)(b * EMBED + c0) * NPOS + pos0;
#pragma unroll
    for (int rr = 0; rr < 8; ++rr) {
        int i = rr * 4 + i0;
        xt[i][j] = xp[(size_t)i * NPOS + j];
    }
    __syncthreads();
    int ii = (t & 15) * 2, jj0 = t >> 4;
    const float kln = -0.07195578415606394f;  // -ln(10000)/128
#pragma unroll
    for (int pp = 0; pp < 4; ++pp) {
        int jj = pp * 16 + jj0;
        int pos = pos0 + jj;
        float v0 = xt[ii][jj], v1 = xt[ii + 1][jj];
        float pe0 = 0.f, pe1 = 0.f;
        if (pos > 0) {
            int c = c0 + ii;
            float a0 = (float)pos * __expf((float)c * kln);
            float a1 = (float)pos * __expf((float)(c + 1) * kln);
            pe0 = __sinf(a0);   // even col -> sin
            pe1 = __cosf(a1);   // odd col -> cos
        }
        unsigned lo = (unsigned short)f2b(v0 + pe0);
        unsigned hi = (unsigned short)f2b(v1 + pe1);
        *reinterpret_cast<unsigned*>(xs + (size_t)(b * NPOS + pos) * EMBED + c0 + ii) =
            lo | (hi << 16);
    }
}

// ---------------- kernel 2: QKV GEMM (64x64 tiles, bias in C-init) ----------------
__global__ __launch_bounds__(256) void gemm_qkv(
        const short* __restrict__ A, const short* __restrict__ Bw,
        const float* __restrict__ bq, const float* __restrict__ bk,
        const float* __restrict__ bv,
        short* __restrict__ qd, short* __restrict__ kd, short* __restrict__ vtd) {
    __shared__ short a_sm[64 * 32];
    __shared__ short b_sm[64 * 32];
    int bx = blockIdx.x;            // 144 x 12
    int bm = bx / 12, bn = bx % 12;
    int m0 = bm * 64, n0 = bn * 64;
    int t = threadIdx.x;
    int lane = t & 63, wid = t >> 6;
    int wm = wid >> 1, wn = wid & 1;
    int l15 = lane & 15, l4 = lane >> 4;

    f32x4 acc[2][2];
#pragma unroll
    for (int ni = 0; ni < 2; ++ni) {
        int jcol = n0 + wn * 32 + ni * 16 + l15;
        int proj = jcol >> 8, jj = jcol & 255;
        float bias = ((proj == 0) ? bq : (proj == 1) ? bk : bv)[jj];
        f32x4 bi = {bias, bias, bias, bias};
        acc[0][ni] = bi;
        acc[1][ni] = bi;
    }

    int srow = t >> 2, sblk = t & 3;
    int ssw = (sblk ^ ((srow >> 1) & 3)) * 8;
    const short* ag = &A[(size_t)(m0 + srow) * 256 + sblk * 8];
    const short* bg = &Bw[(size_t)(n0 + srow) * 256 + sblk * 8];
    short* al = &a_sm[srow * 32 + ssw];
    short* bl = &b_sm[srow * 32 + ssw];

    for (int ks = 0; ks < 8; ++ks) {
        __syncthreads();
        *(bf16x8*)al = *(const bf16x8*)(ag + ks * 32);
        *(bf16x8*)bl = *(const bf16x8*)(bg + ks * 32);
        __syncthreads();
        bf16x8 af[2], bf[2];
#pragma unroll
        for (int mi = 0; mi < 2; ++mi) {
            int ar = wm * 32 + mi * 16 + l15;
            af[mi] = *(const bf16x8*)&a_sm[ar * 32 + ((l4 ^ ((ar >> 1) & 3)) * 8)];
        }
#pragma unroll
        for (int ni = 0; ni < 2; ++ni) {
            int br = wn * 32 + ni * 16 + l15;
            bf[ni] = *(const bf16x8*)&b_sm[br * 32 + ((l4 ^ ((br >> 1) & 3)) * 8)];
        }
#pragma unroll
        for (int mi = 0; mi < 2; ++mi)
#pragma unroll
            for (int ni = 0; ni < 2; ++ni)
                acc[mi][ni] = __builtin_amdgcn_mfma_f32_16x16x32_bf16(
                    af[mi], bf[ni], acc[mi][ni], 0, 0, 0);
    }

    const float qs = 0.2550348623f;  // log2(e)/sqrt(32)
#pragma unroll
    for (int mi = 0; mi < 2; ++mi) {
        int rowb = m0 + wm * 32 + mi * 16 + l4 * 4;
        int b = rowb / NPOS;
        int pos = rowb - b * NPOS;
#pragma unroll
        for (int ni = 0; ni < 2; ++ni) {
            int jcol = n0 + wn * 32 + ni * 16 + l15;
            int proj = jcol >> 8, jj = jcol & 255;
            int h = jj >> 5, d = jj & 31;
            if (proj == 2) {
                s16x4 pk;
#pragma unroll
                for (int r = 0; r < 4; ++r) pk[r] = f2b(acc[mi][ni][r]);
                *(s16x4*)&vtd[((size_t)(b * NH + h) * DH + d) * NPOS + pos] = pk;
            } else {
                short* dst = (proj == 0) ? qd : kd;
                float sc = (proj == 0) ? qs : 1.0f;
#pragma unroll
                for (int r = 0; r < 4; ++r)
                    dst[((size_t)(b * NH + h) * NPOS + pos + r) * DH + d] =
                        f2b(acc[mi][ni][r] * sc);
            }
        }
    }
}

// ---------------- kernel 3: flash attention (KV-split x2, 4 waves/block) ----------------
// Block = 256 thr: waves {0,1} = pipeline A (KV tiles 0..17), waves {2,3} = pipeline B
// (tiles 18..35). Within a pipeline each wave owns 32 q-rows; the pair cooperatively
// stages K/V via global_load_lds (2-deep, counted vmcnt). Static-max softmax makes the
// KV reduction associative -> cross-pipe combine via LDS at the end.
// Q,K [bh][n][dh] bf16 (Q pre-scaled by log2e/sqrt(dh)), VT [bh][dh][n] -> AO bf16

static __device__ __forceinline__ void issue_tile(
        const short* kg, const short* vg, int kv0, short* kd, short* vd) {
    gl_lds16(kg + (size_t)kv0 * DH,        kd);
    gl_lds16(kg + (size_t)(kv0 + 32) * DH, kd + 1024);
    gl_lds16(vg + kv0,                     vd);
    gl_lds16(vg + kv0 + 16 * NPOS,         vd + 1024);
}

__global__ __launch_bounds__(256) void attn_fwd(
        const short* __restrict__ Q, const short* __restrict__ K,
        const short* __restrict__ VT, short* __restrict__ AO) {
    // 32 KB: shorts [0,4096) K_A[2][2048] | [4096,8192) V_A[2][2048]
    //        [8192,12288) K_B | [12288,16384) V_B ; reused for the combine epilogue
    __shared__ short smem[16384];

    int bx0 = blockIdx.x;
    int bx = (bx0 & 7) * 144 + (bx0 >> 3);   // 1152 = 8*144: bijective, same-bh -> same XCD
    int bh = bx / 36, qt0 = bx % 36;
    int q0 = qt0 * 64;
    int t = threadIdx.x, lane = t & 63, wid = t >> 6;
    int pipe = wid >> 1, rg = wid & 1;
    int l15 = lane & 15, l4 = lane >> 4;

    // Q B-frags: row-group rg owns qrows q0 + rg*32 + [0,32)
    const short* Qb = Q + ((size_t)bh * NPOS + q0 + rg * 32) * DH;
    bf16x8 qf[2];
    qf[0] = *(const bf16x8*)&Qb[l15 * DH + l4 * 8];
    qf[1] = *(const bf16x8*)&Qb[(16 + l15) * DH + l4 * 8];

    // staging sources (pre-swizzled global addr; LDS dest linear); u = thread-in-pipe
    int u = t & 127;
    int krow = u >> 2, kblk = u & 3;   // rows 0..31 (+32 in 2nd DMA)
    const short* kg = K + ((size_t)bh * NPOS + krow) * DH + ((kblk ^ ((krow >> 1) & 3)) * 8);
    int vrow = u >> 3, vblk = u & 7;   // d 0..15 (+16)
    const short* vg = VT + ((size_t)bh * DH + vrow) * NPOS + ((vblk ^ (vrow & 7)) * 8);

    short* kst = smem + pipe * 8192;          // [2][2048]
    short* vst = kst + 4096;                  // [2][2048]
    int dbase = rg * 512;                     // per-wave LDS dest base within a buffer
    int kvb = pipe * 1152;                    // pipeline B starts at key 1152

    f32x4 zero = {0.f, 0.f, 0.f, 0.f};
    f32x4 o[2][2];
    o[0][0] = zero; o[0][1] = zero; o[1][0] = zero; o[1][1] = zero;
    float ls[2] = {0.f, 0.f};
    const float MB = -17.312340490667561f;  // -12*log2(e)
    const f32x4 mb = {MB, MB, MB, MB};

    // read-side swizzles (row-group independent)
    int ksw = (l4 ^ ((l15 >> 1) & 3)) * 8;
    int vsw0 = (l4 ^ (l15 & 7)) * 8;
    int vsw1 = ((4 + l4) ^ (l15 & 7)) * 8;

    issue_tile(kg, vg, kvb, kst + dbase, vst + dbase);

#pragma unroll 1
    for (int tt = 0; tt < 18; ++tt) {
        int cur = tt & 1;
        if (tt + 1 < 18) {
            issue_tile(kg, vg, kvb + (tt + 1) * 64,
                       kst + (cur ^ 1) * 2048 + dbase, vst + (cur ^ 1) * 2048 + dbase);
            asm volatile("s_waitcnt vmcnt(4)" ::: "memory");
        } else {
            asm volatile("s_waitcnt vmcnt(0)" ::: "memory");
        }
        __builtin_amdgcn_s_barrier();
        asm volatile("" ::: "memory");

        const short* kb = kst + cur * 2048;
        const short* vb = vst + cur * 2048;

        bf16x8 kf[4], vf[4];
        kf[0] = *(const bf16x8*)&kb[(l15)      * 32 + ksw];
        kf[1] = *(const bf16x8*)&kb[(16 + l15) * 32 + ksw];
        kf[2] = *(const bf16x8*)&kb[(32 + l15) * 32 + ksw];
        kf[3] = *(const bf16x8*)&kb[(48 + l15) * 32 + ksw];
        vf[0] = *(const bf16x8*)&vb[(l15)      * 64 + vsw0];
        vf[1] = *(const bf16x8*)&vb[(16 + l15) * 64 + vsw0];
        vf[2] = *(const bf16x8*)&vb[(l15)      * 64 + vsw1];
        vf[3] = *(const bf16x8*)&vb[(16 + l15) * 64 + vsw1];

#pragma unroll
        for (int qt = 0; qt < 2; ++qt) {
            f32x4 s0 = __builtin_amdgcn_mfma_f32_16x16x32_bf16(kf[0], qf[qt], mb, 0, 0, 0);
            f32x4 s1 = __builtin_amdgcn_mfma_f32_16x16x32_bf16(kf[1], qf[qt], mb, 0, 0, 0);
            f32x4 s2 = __builtin_amdgcn_mfma_f32_16x16x32_bf16(kf[2], qf[qt], mb, 0, 0, 0);
            f32x4 s3 = __builtin_amdgcn_mfma_f32_16x16x32_bf16(kf[3], qf[qt], mb, 0, 0, 0);

            float e00 = fexp2(s0[0]), e01 = fexp2(s0[1]), e02 = fexp2(s0[2]), e03 = fexp2(s0[3]);
            float e10 = fexp2(s1[0]), e11 = fexp2(s1[1]), e12 = fexp2(s1[2]), e13 = fexp2(s1[3]);
            float e20 = fexp2(s2[0]), e21 = fexp2(s2[1]), e22 = fexp2(s2[2]), e23 = fexp2(s2[3]);
            float e30 = fexp2(s3[0]), e31 = fexp2(s3[1]), e32 = fexp2(s3[2]), e33 = fexp2(s3[3]);
            ls[qt] += (((e00 + e01) + (e02 + e03)) + ((e10 + e11) + (e12 + e13)))
                    + (((e20 + e21) + (e22 + e23)) + ((e30 + e31) + (e32 + e33)));

            unsigned p00 = cvtpk(e00, e01), p01 = cvtpk(e02, e03);
            unsigned p10 = cvtpk(e10, e11), p11 = cvtpk(e12, e13);
            unsigned p20 = cvtpk(e20, e21), p21 = cvtpk(e22, e23);
            unsigned p30 = cvtpk(e30, e31), p31 = cvtpk(e32, e33);

            unsigned a0 = p00, b0 = p10;
            plswap32(a0, b0); plswap16(a0, b0);
            unsigned a1 = p01, b1 = p11;
            plswap32(a1, b1); plswap16(a1, b1);
            u32x4 fr0 = {a0, a1, b0, b1};
            bf16x8 pf0 = __builtin_bit_cast(bf16x8, fr0);
            unsigned c0 = p20, d0 = p30;
            plswap32(c0, d0); plswap16(c0, d0);
            unsigned c1 = p21, d1 = p31;
            plswap32(c1, d1); plswap16(c1, d1);
            u32x4 fr1 = {c0, c1, d0, d1};
            bf16x8 pf1 = __builtin_bit_cast(bf16x8, fr1);

            o[0][qt] = __builtin_amdgcn_mfma_f32_16x16x32_bf16(vf[0], pf0, o[0][qt], 0, 0, 0);
            o[1][qt] = __builtin_amdgcn_mfma_f32_16x16x32_bf16(vf[1], pf0, o[1][qt], 0, 0, 0);
            o[0][qt] = __builtin_amdgcn_mfma_f32_16x16x32_bf16(vf[2], pf1, o[0][qt], 0, 0, 0);
            o[1][qt] = __builtin_amdgcn_mfma_f32_16x16x32_bf16(vf[3], pf1, o[1][qt], 0, 0, 0);
        }
        asm volatile("" ::: "memory");
        __builtin_amdgcn_s_barrier();
        asm volatile("" ::: "memory");
    }

    // intra-wave l reduce (over l4 groups)
    float l0 = ls[0];
    l0 += __shfl_xor(l0, 16);
    l0 += __shfl_xor(l0, 32);
    float l1 = ls[1];
    l1 += __shfl_xor(l1, 16);
    l1 += __shfl_xor(l1, 32);

    // cross-pipe combine via (dead) staging LDS
    f32x4* osm4 = (f32x4*)smem;               // bytes [0, 8192)
    float* lsm = (float*)(smem + 4096);       // bytes [8192, 9216)
    if (pipe == 1) {
        lsm[(rg * 2 + 0) * 64 + lane] = l0;
        lsm[(rg * 2 + 1) * 64 + lane] = l1;
#pragma unroll
        for (int qt = 0; qt < 2; ++qt)
#pragma unroll
            for (int dt2 = 0; dt2 < 2; ++dt2)
                osm4[((rg * 2 + qt) * 2 + dt2) * 64 + lane] = o[dt2][qt];
    }
    __syncthreads();
    if (pipe == 0) {
        l0 += lsm[(rg * 2 + 0) * 64 + lane];
        l1 += lsm[(rg * 2 + 1) * 64 + lane];
        float inv0 = __builtin_amdgcn_rcpf(l0);
        float inv1 = __builtin_amdgcn_rcpf(l1);
        int b = bh >> 3, h = bh & 7;
#pragma unroll
        for (int qt = 0; qt < 2; ++qt) {
            int qrow = q0 + rg * 32 + qt * 16 + l15;
            float inv = (qt == 0) ? inv0 : inv1;
            size_t obase = ((size_t)b * NPOS + qrow) * EMBED + h * DH;
#pragma unroll
            for (int dt2 = 0; dt2 < 2; ++dt2) {
                f32x4 ot = o[dt2][qt] + osm4[((rg * 2 + qt) * 2 + dt2) * 64 + lane];
                unsigned x0 = cvtpk(ot[0] * inv, ot[1] * inv);
                unsigned x1 = cvtpk(ot[2] * inv, ot[3] * inv);
                *(unsigned long long*)&AO[obase + dt2 * 16 + l4 * 4] =
                    (unsigned long long)x0 | ((unsigned long long)x1 << 32);
            }
        }
    }
}

// ---------------- kernel 4: out projection + transpose (32x64 tiles) ----------------
__global__ __launch_bounds__(256) void gemm_out(
        const short* __restrict__ A, const short* __restrict__ Bw,
        const float* __restrict__ bo, float* __restrict__ out) {
    __shared__ short a_sm[32 * 32];
    __shared__ short b_sm[64 * 32];
    int bx = blockIdx.x;             // 288 x 4
    int bm = bx >> 2, bn = bx & 3;
    int m0 = bm * 32, n0 = bn * 64;
    int t = threadIdx.x;
    int lane = t & 63, wid = t >> 6;
    int wm = wid >> 1, wn = wid & 1;
    int l15 = lane & 15, l4 = lane >> 4;

    f32x4 acc[2];
#pragma unroll
    for (int ni = 0; ni < 2; ++ni) {
        float bias = bo[n0 + wn * 32 + ni * 16 + l15];
        f32x4 bi = {bias, bias, bias, bias};
        acc[ni] = bi;
    }

    int srow = t >> 2, sblk = t & 3;
    int ssw = (sblk ^ ((srow >> 1) & 3)) * 8;
    const short* ag = &A[(size_t)(m0 + srow) * 256 + sblk * 8];
    const short* bg = &Bw[(size_t)(n0 + srow) * 256 + sblk * 8];
    short* al = &a_sm[srow * 32 + ssw];
    short* bl = &b_sm[srow * 32 + ssw];

    for (int ks = 0; ks < 8; ++ks) {
        __syncthreads();
        if (t < 128) *(bf16x8*)al = *(const bf16x8*)(ag + ks * 32);
        *(bf16x8*)bl = *(const bf16x8*)(bg + ks * 32);
        __syncthreads();
        int ar = wm * 16 + l15;
        bf16x8 af = *(const bf16x8*)&a_sm[ar * 32 + ((l4 ^ ((ar >> 1) & 3)) * 8)];
        bf16x8 bf[2];
#pragma unroll
        for (int ni = 0; ni < 2; ++ni) {
            int br = wn * 32 + ni * 16 + l15;
            bf[ni] = *(const bf16x8*)&b_sm[br * 32 + ((l4 ^ ((br >> 1) & 3)) * 8)];
        }
#pragma unroll
        for (int ni = 0; ni < 2; ++ni)
            acc[ni] = __builtin_amdgcn_mfma_f32_16x16x32_bf16(af, bf[ni], acc[ni], 0, 0, 0);
    }

    int rowb = m0 + wm * 16 + l4 * 4;
    int b = rowb / NPOS;
    int pos = rowb - b * NPOS;
#pragma unroll
    for (int ni = 0; ni < 2; ++ni) {
        int jcol = n0 + wn * 32 + ni * 16 + l15;
        *(f32x4*)&out[((size_t)(b * EMBED) + jcol) * NPOS + pos] = acc[ni];
    }
}

extern "C" void kernel_launch(void* const* d_in, const int* in_sizes, int n_in,
                              void* d_out, int out_size, void* d_ws, size_t ws_size,
                              hipStream_t stream) {
    const float* x  = (const float*)d_in[0];
    const float* wq = (const float*)d_in[1];
    const float* bq = (const float*)d_in[2];
    const float* wk = (const float*)d_in[3];
    const float* bk = (const float*)d_in[4];
    const float* wv = (const float*)d_in[5];
    const float* bv = (const float*)d_in[6];
    const float* wo = (const float*)d_in[7];
    const float* bo = (const float*)d_in[8];

    char* ws = (char*)d_ws;
    short* wqkv = (short*)(ws);               // 768*256*2   = 393216
    short* wob  = (short*)(ws + 393216);      // 256*256*2   = 131072
    short* xs   = (short*)(ws + 524288);      // 9216*256*2  = 4718592
    short* qb   = (short*)(ws + 5242880);     // 4718592
    short* kb   = (short*)(ws + 9961472);     // 4718592
    short* vtb  = (short*)(ws + 14680064);    // 4718592
    short* ao   = (short*)(ws + 19398656);    // 4718592 -> total 24117248
    float* out  = (float*)d_out;

    hipLaunchKernelGGL(prep_all, dim3(2176), dim3(256), 0, stream,
                       x, wq, wk, wv, wo, wqkv, wob, xs);
    hipLaunchKernelGGL(gemm_qkv, dim3(1728), dim3(256), 0, stream,
                       xs, wqkv, bq, bk, bv, qb, kb, vtb);
    hipLaunchKernelGGL(attn_fwd, dim3(1152), dim3(256), 0, stream, qb, kb, vtb, ao);
    hipLaunchKernelGGL(gemm_out, dim3(1152), dim3(256), 0, stream, ao, wob, bo, out);
}